// Round 7
// baseline (315.622 us; speedup 1.0000x reference)
//
#include <hip/hip_runtime.h>
#include <hip/hip_bf16.h>
#include <stdint.h>

typedef unsigned short u16;
typedef __attribute__((ext_vector_type(8))) short s16x8;
typedef __attribute__((ext_vector_type(4))) float f32x4;

#define B_ 2
#define S_ 2048
#define H_ 2304
#define NH_ 8
#define NKV_ 4
#define HD_ 256

__device__ __forceinline__ float bf2f(u16 u) {
  union { uint32_t i; float f; } x; x.i = ((uint32_t)u) << 16; return x.f;
}
__device__ __forceinline__ u16 f2bf(float f) {
  union { float f; uint32_t i; } x; x.f = f;
  uint32_t u = x.i;
  return (u16)((u + 0x7fffu + ((u >> 16) & 1u)) >> 16);
}

__device__ __forceinline__ void async16(const void* g, void* l) {
  __builtin_amdgcn_global_load_lds((const __attribute__((address_space(1))) uint32_t*)g,
                                   (__attribute__((address_space(3))) uint32_t*)l, 16, 0, 0);
}

__device__ __forceinline__ f32x4 mfma16(s16x8 a, s16x8 b, f32x4 c) {
  return __builtin_amdgcn_mfma_f32_16x16x32_bf16(a, b, c, 0, 0, 0);
}

// ---------------- fp32 -> bf16 elementwise convert ----------------
__global__ void f32_to_bf16(const float* __restrict__ in, u16* __restrict__ out, size_t n) {
  size_t i = ((size_t)blockIdx.x * blockDim.x + threadIdx.x) * 4;
  if (i + 3 < n) {
    float4 v = *(const float4*)(in + i);
    ushort4 o;
    o.x = f2bf(v.x); o.y = f2bf(v.y); o.z = f2bf(v.z); o.w = f2bf(v.w);
    *(ushort4*)(out + i) = o;
  }
}

// ---------------- transpose fp32 in -> bf16 out: in[R][C] -> out[C][R] ----------------
__global__ void transpose_f32_bf16(const float* __restrict__ in, u16* __restrict__ out, int R, int C) {
  __shared__ u16 tile[32][33];
  int c0 = blockIdx.x * 32, r0 = blockIdx.y * 32;
  int x = threadIdx.x, y = threadIdx.y;
#pragma unroll
  for (int j = 0; j < 32; j += 8)
    tile[y + j][x] = f2bf(in[(size_t)(r0 + y + j) * C + c0 + x]);
  __syncthreads();
#pragma unroll
  for (int j = 0; j < 32; j += 8)
    out[(size_t)(c0 + y + j) * R + r0 + x] = tile[x][y + j];
}

// ------- strided-batch bf16 transpose: in[z*zin + r*istride + c] -> out[z*zout + c*R + r] -------
__global__ void transpose_bf16_s(const u16* __restrict__ in, u16* __restrict__ out, int R, int C,
                                 int istride, size_t zin, size_t zout) {
  __shared__ u16 tile[32][33];
  in += (size_t)blockIdx.z * zin;
  out += (size_t)blockIdx.z * zout;
  int c0 = blockIdx.x * 32, r0 = blockIdx.y * 32;
  int x = threadIdx.x, y = threadIdx.y;
#pragma unroll
  for (int j = 0; j < 32; j += 8)
    tile[y + j][x] = in[(size_t)(r0 + y + j) * istride + c0 + x];
  __syncthreads();
#pragma unroll
  for (int j = 0; j < 32; j += 8)
    out[(size_t)(c0 + y + j) * R + r0 + x] = tile[x][y + j];
}

// ================= 256x256 deep-pipelined GEMM: C = A[M][Kd] * BT[N][Kd]^T =================
template <bool F32OUT>
__global__ __launch_bounds__(512) void gemm256(const u16* __restrict__ A, const u16* __restrict__ BT,
                                               void* __restrict__ Cout, int M, int N, int Kd) {
  __shared__ u16 As[2][256 * 64];
  __shared__ u16 Bs[2][256 * 64];
  int tid = threadIdx.x, lane = tid & 63, wave = tid >> 6;
  int nT = gridDim.x * gridDim.y;
  int bid = blockIdx.y * gridDim.x + blockIdx.x;
  int tile = (bid & 7) * (nT >> 3) + (bid >> 3);        // XCD swizzle (nT % 8 == 0)
  int bn = (tile % gridDim.x) * 256;
  int bm = (tile / gridDim.x) * 256;
  int wm = (wave >> 2) * 128, wn = (wave & 3) * 64;
  int fr = lane & 15, fq = lane >> 4;
  f32x4 acc[8][4];
#pragma unroll
  for (int i = 0; i < 8; i++)
#pragma unroll
    for (int j = 0; j < 4; j++) acc[i][j] = (f32x4){0.f, 0.f, 0.f, 0.f};

  int srow = tid >> 3, sslot = tid & 7;
  int scol = (sslot * 8) ^ ((srow & 7) << 3);           // pre-swizzled source col (u16 units)
  const u16* Ab = A + (size_t)(bm + srow) * Kd + scol;
  const u16* Bb = BT + (size_t)(bn + srow) * Kd + scol;

  auto stage = [&](int buf, int k0) {
#pragma unroll
    for (int i = 0; i < 4; i++) {
      async16(Ab + (size_t)i * 64 * Kd + k0, (char*)&As[buf][0] + wave * 1024 + i * 8192);
      async16(Bb + (size_t)i * 64 * Kd + k0, (char*)&Bs[buf][0] + wave * 1024 + i * 8192);
    }
  };

  int NT = Kd >> 6;
  int rsw = (fr & 7) << 3;
  stage(0, 0);
  for (int t = 0; t < NT; ++t) {
    if (t + 1 < NT) {
      stage((t + 1) & 1, (t + 1) << 6);
      asm volatile("s_waitcnt vmcnt(8)" ::: "memory");
    } else {
      asm volatile("s_waitcnt vmcnt(0)" ::: "memory");
    }
    __builtin_amdgcn_sched_barrier(0);
    __builtin_amdgcn_s_barrier();
    __builtin_amdgcn_sched_barrier(0);
    const u16* Ap = &As[t & 1][0];
    const u16* Bp = &Bs[t & 1][0];
    __builtin_amdgcn_s_setprio(1);
    s16x8 bfr[4][2];
#pragma unroll
    for (int j = 0; j < 4; j++)
#pragma unroll
      for (int s = 0; s < 2; s++)
        bfr[j][s] = *(const s16x8*)&Bp[(wn + j * 16 + fr) * 64 + ((s * 32 + fq * 8) ^ rsw)];
#pragma unroll
    for (int i = 0; i < 8; i++) {
      s16x8 a0 = *(const s16x8*)&Ap[(wm + i * 16 + fr) * 64 + ((fq * 8) ^ rsw)];
      s16x8 a1 = *(const s16x8*)&Ap[(wm + i * 16 + fr) * 64 + ((32 + fq * 8) ^ rsw)];
#pragma unroll
      for (int j = 0; j < 4; j++) {
        acc[i][j] = mfma16(a0, bfr[j][0], acc[i][j]);
        acc[i][j] = mfma16(a1, bfr[j][1], acc[i][j]);
      }
    }
    __builtin_amdgcn_s_setprio(0);
    asm volatile("s_waitcnt lgkmcnt(0)" ::: "memory");
    __builtin_amdgcn_sched_barrier(0);
    __builtin_amdgcn_s_barrier();
  }

#pragma unroll
  for (int i = 0; i < 8; i++)
#pragma unroll
    for (int j = 0; j < 4; j++)
#pragma unroll
      for (int r = 0; r < 4; r++) {
        int row = bm + wm + i * 16 + fq * 4 + r;
        int col = bn + wn + j * 16 + fr;
        if (F32OUT) ((float*)Cout)[(size_t)row * N + col] = acc[i][j][r];
        else        ((u16*)Cout)[(size_t)row * N + col] = f2bf(acc[i][j][r]);
      }
}

// ================= 128x128 pipelined GEMM (for N=2304 out-proj) =================
template <bool F32OUT>
__global__ __launch_bounds__(256) void gemm128(const u16* __restrict__ A, const u16* __restrict__ BT,
                                               void* __restrict__ Cout, int M, int N, int Kd) {
  __shared__ u16 As[2][128 * 32];
  __shared__ u16 Bs[2][128 * 32];
  int tid = threadIdx.x, lane = tid & 63, wave = tid >> 6;
  int nT = gridDim.x * gridDim.y;
  int bid = blockIdx.y * gridDim.x + blockIdx.x;
  int tile = (bid & 7) * (nT >> 3) + (bid >> 3);
  int bn = (tile % gridDim.x) * 128;
  int bm = (tile / gridDim.x) * 128;
  int wm = (wave >> 1) * 64, wn = (wave & 1) * 64;
  int fr = lane & 15, fq = lane >> 4;
  f32x4 acc[4][4];
#pragma unroll
  for (int i = 0; i < 4; i++)
#pragma unroll
    for (int j = 0; j < 4; j++) acc[i][j] = (f32x4){0.f, 0.f, 0.f, 0.f};

  int srow = tid >> 2, sslot = tid & 3;
  int scol = (sslot * 8) ^ ((srow & 3) << 3);
  const u16* Ab = A + (size_t)(bm + srow) * Kd + scol;
  const u16* Bb = BT + (size_t)(bn + srow) * Kd + scol;

  auto stage = [&](int buf, int k0) {
    async16(Ab + k0, (char*)&As[buf][0] + wave * 1024);
    async16(Ab + (size_t)64 * Kd + k0, (char*)&As[buf][0] + wave * 1024 + 4096);
    async16(Bb + k0, (char*)&Bs[buf][0] + wave * 1024);
    async16(Bb + (size_t)64 * Kd + k0, (char*)&Bs[buf][0] + wave * 1024 + 4096);
  };

  int NT = Kd >> 5;
  int rsw = (fr & 3) << 3;
  stage(0, 0);
  for (int t = 0; t < NT; ++t) {
    if (t + 1 < NT) {
      stage((t + 1) & 1, (t + 1) << 5);
      asm volatile("s_waitcnt vmcnt(4)" ::: "memory");
    } else {
      asm volatile("s_waitcnt vmcnt(0)" ::: "memory");
    }
    __builtin_amdgcn_sched_barrier(0);
    __builtin_amdgcn_s_barrier();
    __builtin_amdgcn_sched_barrier(0);
    const u16* Ap = &As[t & 1][0];
    const u16* Bp = &Bs[t & 1][0];
    __builtin_amdgcn_s_setprio(1);
    s16x8 af[4], bv[4];
#pragma unroll
    for (int i = 0; i < 4; i++) af[i] = *(const s16x8*)&Ap[(wm + i * 16 + fr) * 32 + ((fq * 8) ^ rsw)];
#pragma unroll
    for (int j = 0; j < 4; j++) bv[j] = *(const s16x8*)&Bp[(wn + j * 16 + fr) * 32 + ((fq * 8) ^ rsw)];
#pragma unroll
    for (int i = 0; i < 4; i++)
#pragma unroll
      for (int j = 0; j < 4; j++)
        acc[i][j] = mfma16(af[i], bv[j], acc[i][j]);
    __builtin_amdgcn_s_setprio(0);
    asm volatile("s_waitcnt lgkmcnt(0)" ::: "memory");
    __builtin_amdgcn_sched_barrier(0);
    __builtin_amdgcn_s_barrier();
  }
#pragma unroll
  for (int i = 0; i < 4; i++)
#pragma unroll
    for (int j = 0; j < 4; j++)
#pragma unroll
      for (int r = 0; r < 4; r++) {
        int row = bm + wm + i * 16 + fq * 4 + r;
        int col = bn + wn + j * 16 + fr;
        if (F32OUT) ((float*)Cout)[(size_t)row * N + col] = acc[i][j][r];
        else        ((u16*)Cout)[(size_t)row * N + col] = f2bf(acc[i][j][r]);
      }
}

// ---------------- RoPE sin/cos table: [pos 0..S-1][d 0..127] f32 ----------------
__global__ void rope_table(float* __restrict__ ct, float* __restrict__ st) {
  int t = blockIdx.x * blockDim.x + threadIdx.x;   // t = p*128 + d
  int d = t & 127;
  int p = t >> 7;
  float invf = exp2f(-(float)d * 0.1038102530f); // log2(10000)/128
  float f = (float)p * invf;
  float s, c;
  sincosf(f, &s, &c);
  ct[t] = c;
  st[t] = s;
}

// ---------------- RoPE on K columns of fused QKV (8 pairs per thread) ----------------
__global__ void rope_k(u16* __restrict__ QKV, const int* __restrict__ pos_ids,
                       const float* __restrict__ ct, const float* __restrict__ st) {
  int t = blockIdx.x * blockDim.x + threadIdx.x;   // 4096 rows * 4 heads * 16 dgroups
  int dg = t & 15, h = (t >> 4) & 3, row = t >> 6;
  u16* p1 = QKV + (size_t)row * 4096 + 2048 + h * 256 + dg * 8;
  u16* p2 = p1 + 128;
  int pos = pos_ids[row];
  const float* ctp = ct + pos * 128 + dg * 8;
  const float* stp = st + pos * 128 + dg * 8;
  s16x8 v1 = *(const s16x8*)p1, v2 = *(const s16x8*)p2;
#pragma unroll
  for (int j = 0; j < 8; j++) {
    float c = ctp[j], s = stp[j];
    float a = bf2f((u16)v1[j]);
    float b = bf2f((u16)v2[j]);
    v1[j] = (short)f2bf(a * c - b * s);
    v2[j] = (short)f2bf(b * c + a * s);
  }
  *(s16x8*)p1 = v1;
  *(s16x8*)p2 = v2;
}

// ---------------- flash attention, softcap, fixed-max softmax, swizzled LDS ----------
// Balanced flat grid (512): id<256 -> qt=31-(id>>4) (heavy, dispatched first), else qt=(id-256)>>4.
// Pairs (id, id+256): work sums to 66 tiles AND share (b,h) -> L2-resident KV per XCD.
// Q roped in-register from table. block 256 = 4 waves x 16 q-rows. KVBLK=32, double-buffered.
__global__ __launch_bounds__(256) void attn_kernel(const u16* __restrict__ QKV, const u16* __restrict__ VT,
                                                   const int* __restrict__ amask, const int* __restrict__ pos_ids,
                                                   const float* __restrict__ ct, const float* __restrict__ st,
                                                   u16* __restrict__ O) {
  __shared__ u16 Kl[2][32 * 256];   // [buf][key][hd]  swizzled ^((key&7)<<3)
  __shared__ u16 Vl[2][256 * 32];   // [buf][hd][key]  swizzled ^((hd&3)<<3)
  __shared__ u16 Pl[4][16 * 40];    // per-wave P, rows padded to 80B
  int id = blockIdx.x;
  int qt, bh;
  if (id < 256) { qt = 31 - (id >> 4); bh = id & 15; }
  else          { qt = (id - 256) >> 4; bh = (id - 256) & 15; }
  int b = bh >> 3, h = bh & 7, g = h >> 1;
  int tid = threadIdx.x, lane = tid & 63, wave = tid >> 6;
  int fr = lane & 15, fq = lane >> 4;
  int q0 = qt * 64;

  // ---- load Q row fragment + apply RoPE in-register (pairs (d,d+128) are lane-local) ----
  int qrow_g = b * S_ + q0 + wave * 16 + fr;
  s16x8 qr[8];
  const u16* qb = QKV + (size_t)qrow_g * 4096 + h * 256 + fq * 8;
#pragma unroll
  for (int kk = 0; kk < 8; kk++) qr[kk] = *(const s16x8*)(qb + kk * 32);
  int pos = pos_ids[qrow_g];
  const float* ctp = ct + pos * 128 + fq * 8;
  const float* stp = st + pos * 128 + fq * 8;
  s16x8 qf[8];
#pragma unroll
  for (int kk = 0; kk < 4; kk++) {
#pragma unroll
    for (int j = 0; j < 8; j++) {
      float c = ctp[kk * 32 + j], s = stp[kk * 32 + j];
      float a = bf2f((u16)qr[kk][j]);
      float bb = bf2f((u16)qr[kk + 4][j]);
      qf[kk][j]     = (short)f2bf((a * c - bb * s) * 0.0625f);   // 1/sqrt(256)
      qf[kk + 4][j] = (short)f2bf((bb * c + a * s) * 0.0625f);
    }
  }

  f32x4 zero4 = {0.f, 0.f, 0.f, 0.f};
  f32x4 oacc[16];
#pragma unroll
  for (int i = 0; i < 16; i++) oacc[i] = zero4;
  f32x4 lacc = zero4;                                     // softmax denominator via ones-MFMA
  s16x8 onesv;
#pragma unroll
  for (int i = 0; i < 8; i++) onesv[i] = (short)0x3F80;   // bf16 1.0

  const u16* Kbase = QKV + (size_t)b * S_ * 4096 + 2048 + g * 256;
  const u16* Vbase = VT + (size_t)(b * 4 + g) * 256 * S_;
  const int* amp = amask + b * S_;

  auto stage = [&](int buf, int k0) {
#pragma unroll
    for (int it = 0; it < 4; ++it) {
      int rl = it * 2 + (lane >> 5);
      int kce = ((lane & 31) * 8) ^ ((rl & 7) << 3);
      async16(Kbase + (size_t)(k0 + wave * 8 + rl) * 4096 + kce,
              (char*)&Kl[buf][0] + wave * 4096 + it * 1024);
      int dl = wave * 64 + it * 16 + (lane >> 2);
      int vce = ((lane & 3) * 8) ^ (((lane >> 2) & 3) << 3);
      async16(Vbase + (size_t)dl * 2048 + k0 + vce,
              (char*)&Vl[buf][0] + wave * 4096 + it * 1024);
    }
  };

  int nt = 2 * qt + 2;                                        // 32-key tiles
  stage(0, 0);
  __syncthreads();
  int buf = 0;
  int ksw = (fr & 7) << 3;
  int vsw = (fr & 3) << 3;
  for (int t = 0; t < nt; ++t) {
    int k0 = t * 32;
    if (t + 1 < nt) stage(buf ^ 1, k0 + 32);
    int am0 = amp[k0 + fr];
    int am1 = amp[k0 + 16 + fr];

    f32x4 s0 = zero4, s1 = zero4;
#pragma unroll
    for (int kk = 0; kk < 8; kk++) {
      s16x8 b0 = *(const s16x8*)&Kl[buf][fr * 256 + ((kk * 32 + fq * 8) ^ ksw)];
      s16x8 b1 = *(const s16x8*)&Kl[buf][(16 + fr) * 256 + ((kk * 32 + fq * 8) ^ ksw)];
      s0 = mfma16(qf[kk], b0, s0);
      s1 = mfma16(qf[kk], b1, s1);
    }

    bool needmask = (t >= nt - 2);
#pragma unroll
    for (int r = 0; r < 4; r++) {
      int qrow = fq * 4 + r;
      int qg = q0 + wave * 16 + qrow;
      // p = exp(50*tanh(s/50) - 50) = 2^(-144.2695/(2^(0.0577078*s)+1))   [fixed max = 50]
      float e20 = exp2f(s0[r] * 0.05770780164f);
      float e21 = exp2f(s1[r] * 0.05770780164f);
      float p0 = exp2f(__fdividef(-144.26950409f, e20 + 1.f));
      float p1 = exp2f(__fdividef(-144.26950409f, e21 + 1.f));
      bool ok0 = (am0 > 0) && (!needmask || (k0 + fr) <= qg);
      bool ok1 = (am1 > 0) && (!needmask || (k0 + 16 + fr) <= qg);
      p0 = ok0 ? p0 : 0.f;
      p1 = ok1 ? p1 : 0.f;
      Pl[wave][qrow * 40 + fr] = f2bf(p0);
      Pl[wave][qrow * 40 + 16 + fr] = f2bf(p1);
    }
    asm volatile("s_waitcnt lgkmcnt(0)" ::: "memory");
    __builtin_amdgcn_sched_barrier(0);

    s16x8 pf = *(const s16x8*)&Pl[wave][fr * 40 + fq * 8];
    lacc = mfma16(pf, onesv, lacc);
#pragma unroll
    for (int df = 0; df < 16; df++) {
      s16x8 vv = *(const s16x8*)&Vl[buf][(df * 16 + fr) * 32 + ((fq * 8) ^ vsw)];
      oacc[df] = mfma16(pf, vv, oacc[df]);
    }
    __syncthreads();
    buf ^= 1;
  }

  float rinv[4];
#pragma unroll
  for (int r = 0; r < 4; r++) rinv[r] = 1.0f / lacc[r];
#pragma unroll
  for (int df = 0; df < 16; df++) {
#pragma unroll
    for (int r = 0; r < 4; r++) {
      float ov = oacc[df][r] * rinv[r];
      O[(size_t)(b * S_ + q0 + wave * 16 + fq * 4 + r) * 2048 + h * 256 + df * 16 + fr] = f2bf(ov);
    }
  }
}

extern "C" void kernel_launch(void* const* d_in, const int* in_sizes, int n_in,
                              void* d_out, int out_size, void* d_ws, size_t ws_size,
                              hipStream_t stream) {
  const float* X   = (const float*)d_in[0];   // [B,S,H] fp32
  const int* amask = (const int*)d_in[1];
  const int* pos   = (const int*)d_in[2];
  const float* Wq  = (const float*)d_in[3];
  const float* Wk  = (const float*)d_in[4];
  const float* Wv  = (const float*)d_in[5];
  const float* Wo  = (const float*)d_in[6];
  float* out = (float*)d_out;                 // [B,S,H] fp32

  char* ws = (char*)d_ws;
  size_t off = 0;
  auto allocB = [&](size_t bytes) {
    char* p = ws + off;
    off += ((bytes + 255) & ~(size_t)255);
    return p;
  };
  u16* Xb   = (u16*)allocB((size_t)4096 * 2304 * 2);
  u16* WqT  = (u16*)allocB((size_t)2048 * 2304 * 2);   // WqT/WkT/WvT contiguous => fused B^T
  u16* WkT  = (u16*)allocB((size_t)1024 * 2304 * 2);
  u16* WvT  = (u16*)allocB((size_t)1024 * 2304 * 2);
  u16* WoT  = (u16*)allocB((size_t)2304 * 2048 * 2);
  u16* QKV  = (u16*)allocB((size_t)4096 * 4096 * 2);
  u16* VTb  = (u16*)allocB((size_t)4096 * 1024 * 2);
  u16* AO   = (u16*)allocB((size_t)4096 * 2048 * 2);
  float* CT = (float*)allocB((size_t)2048 * 128 * 4);
  float* ST = (float*)allocB((size_t)2048 * 128 * 4);
  if (off > ws_size) return;

  // RoPE table (independent; early)
  rope_table<<<(2048 * 128) / 256, 256, 0, stream>>>(CT, ST);

  // hidden_states fp32 -> bf16
  {
    size_t n = (size_t)4096 * 2304;
    f32_to_bf16<<<(unsigned)((n / 4 + 255) / 256), 256, 0, stream>>>(X, Xb, n);
  }

  dim3 tb(32, 8);
  transpose_f32_bf16<<<dim3(2048 / 32, 2304 / 32), tb, 0, stream>>>(Wq, WqT, 2304, 2048);
  transpose_f32_bf16<<<dim3(1024 / 32, 2304 / 32), tb, 0, stream>>>(Wk, WkT, 2304, 1024);
  transpose_f32_bf16<<<dim3(1024 / 32, 2304 / 32), tb, 0, stream>>>(Wv, WvT, 2304, 1024);
  transpose_f32_bf16<<<dim3(2304 / 32, 2048 / 32), tb, 0, stream>>>(Wo, WoT, 2048, 2304);

  // fused QKV projection (256² pipelined)
  gemm256<false><<<dim3(4096 / 256, 4096 / 256), 512, 0, stream>>>(Xb, WqT, QKV, 4096, 4096, 2304);

  // RoPE on K only (Q roped in-register inside attn)
  rope_k<<<(4096 * 4 * 16) / 256, 256, 0, stream>>>(QKV, pos, CT, ST);

  // V (QKV cols 3072..4095) -> VT[b][kv][d][s]
  transpose_bf16_s<<<dim3(1024 / 32, 2048 / 32, 2), tb, 0, stream>>>(
      QKV + 3072, VTb, 2048, 1024, 4096, (size_t)2048 * 4096, (size_t)1024 * 2048);

  // attention (balanced flat grid)
  attn_kernel<<<dim3(512), 256, 0, stream>>>(QKV, VTb, amask, pos, CT, ST, AO);

  // output projection -> fp32 d_out (128² pipelined)
  gemm128<true><<<dim3(2304 / 128, 4096 / 128), 256, 0, stream>>>(AO, WoT, out, 4096, 2304, 2048);
}

// Round 8
// 303.811 us; speedup vs baseline: 1.0389x; 1.0389x over previous
//
#include <hip/hip_runtime.h>
#include <hip/hip_bf16.h>
#include <stdint.h>

typedef unsigned short u16;
typedef __attribute__((ext_vector_type(8))) short s16x8;
typedef __attribute__((ext_vector_type(4))) float f32x4;

#define B_ 2
#define S_ 2048
#define H_ 2304
#define NH_ 8
#define NKV_ 4
#define HD_ 256

__device__ __forceinline__ float bf2f(u16 u) {
  union { uint32_t i; float f; } x; x.i = ((uint32_t)u) << 16; return x.f;
}
__device__ __forceinline__ u16 f2bf(float f) {
  union { float f; uint32_t i; } x; x.f = f;
  uint32_t u = x.i;
  return (u16)((u + 0x7fffu + ((u >> 16) & 1u)) >> 16);
}

__device__ __forceinline__ void async16(const void* g, void* l) {
  __builtin_amdgcn_global_load_lds((const __attribute__((address_space(1))) uint32_t*)g,
                                   (__attribute__((address_space(3))) uint32_t*)l, 16, 0, 0);
}

__device__ __forceinline__ f32x4 mfma16(s16x8 a, s16x8 b, f32x4 c) {
  return __builtin_amdgcn_mfma_f32_16x16x32_bf16(a, b, c, 0, 0, 0);
}

// ---------------- fp32 -> bf16 elementwise convert ----------------
__global__ void f32_to_bf16(const float* __restrict__ in, u16* __restrict__ out, size_t n) {
  size_t i = ((size_t)blockIdx.x * blockDim.x + threadIdx.x) * 4;
  if (i + 3 < n) {
    float4 v = *(const float4*)(in + i);
    ushort4 o;
    o.x = f2bf(v.x); o.y = f2bf(v.y); o.z = f2bf(v.z); o.w = f2bf(v.w);
    *(ushort4*)(out + i) = o;
  }
}

// ---------------- transpose fp32 in -> bf16 out: in[R][C] -> out[C][R] ----------------
__global__ void transpose_f32_bf16(const float* __restrict__ in, u16* __restrict__ out, int R, int C) {
  __shared__ u16 tile[32][33];
  int c0 = blockIdx.x * 32, r0 = blockIdx.y * 32;
  int x = threadIdx.x, y = threadIdx.y;
#pragma unroll
  for (int j = 0; j < 32; j += 8)
    tile[y + j][x] = f2bf(in[(size_t)(r0 + y + j) * C + c0 + x]);
  __syncthreads();
#pragma unroll
  for (int j = 0; j < 32; j += 8)
    out[(size_t)(c0 + y + j) * R + r0 + x] = tile[x][y + j];
}

// ------- strided-batch bf16 transpose: in[z*zin + r*istride + c] -> out[z*zout + c*R + r] -------
__global__ void transpose_bf16_s(const u16* __restrict__ in, u16* __restrict__ out, int R, int C,
                                 int istride, size_t zin, size_t zout) {
  __shared__ u16 tile[32][33];
  in += (size_t)blockIdx.z * zin;
  out += (size_t)blockIdx.z * zout;
  int c0 = blockIdx.x * 32, r0 = blockIdx.y * 32;
  int x = threadIdx.x, y = threadIdx.y;
#pragma unroll
  for (int j = 0; j < 32; j += 8)
    tile[y + j][x] = in[(size_t)(r0 + y + j) * istride + c0 + x];
  __syncthreads();
#pragma unroll
  for (int j = 0; j < 32; j += 8)
    out[(size_t)(c0 + y + j) * R + r0 + x] = tile[x][y + j];
}

// ================= 256x256 deep-pipelined GEMM: C = A[M][Kd] * BT[N][Kd]^T =================
template <bool F32OUT>
__global__ __launch_bounds__(512) void gemm256(const u16* __restrict__ A, const u16* __restrict__ BT,
                                               void* __restrict__ Cout, int M, int N, int Kd) {
  __shared__ u16 As[2][256 * 64];
  __shared__ u16 Bs[2][256 * 64];
  int tid = threadIdx.x, lane = tid & 63, wave = tid >> 6;
  int nT = gridDim.x * gridDim.y;
  int bid = blockIdx.y * gridDim.x + blockIdx.x;
  int tile = (bid & 7) * (nT >> 3) + (bid >> 3);        // XCD swizzle (nT % 8 == 0)
  int bn = (tile % gridDim.x) * 256;
  int bm = (tile / gridDim.x) * 256;
  int wm = (wave >> 2) * 128, wn = (wave & 3) * 64;
  int fr = lane & 15, fq = lane >> 4;
  f32x4 acc[8][4];
#pragma unroll
  for (int i = 0; i < 8; i++)
#pragma unroll
    for (int j = 0; j < 4; j++) acc[i][j] = (f32x4){0.f, 0.f, 0.f, 0.f};

  int srow = tid >> 3, sslot = tid & 7;
  int scol = (sslot * 8) ^ ((srow & 7) << 3);           // pre-swizzled source col (u16 units)
  const u16* Ab = A + (size_t)(bm + srow) * Kd + scol;
  const u16* Bb = BT + (size_t)(bn + srow) * Kd + scol;

  auto stage = [&](int buf, int k0) {
#pragma unroll
    for (int i = 0; i < 4; i++) {
      async16(Ab + (size_t)i * 64 * Kd + k0, (char*)&As[buf][0] + wave * 1024 + i * 8192);
      async16(Bb + (size_t)i * 64 * Kd + k0, (char*)&Bs[buf][0] + wave * 1024 + i * 8192);
    }
  };

  int NT = Kd >> 6;
  int rsw = (fr & 7) << 3;
  stage(0, 0);
  for (int t = 0; t < NT; ++t) {
    if (t + 1 < NT) {
      stage((t + 1) & 1, (t + 1) << 6);
      asm volatile("s_waitcnt vmcnt(8)" ::: "memory");
    } else {
      asm volatile("s_waitcnt vmcnt(0)" ::: "memory");
    }
    __builtin_amdgcn_sched_barrier(0);
    __builtin_amdgcn_s_barrier();
    __builtin_amdgcn_sched_barrier(0);
    const u16* Ap = &As[t & 1][0];
    const u16* Bp = &Bs[t & 1][0];
    __builtin_amdgcn_s_setprio(1);
    s16x8 bfr[4][2];
#pragma unroll
    for (int j = 0; j < 4; j++)
#pragma unroll
      for (int s = 0; s < 2; s++)
        bfr[j][s] = *(const s16x8*)&Bp[(wn + j * 16 + fr) * 64 + ((s * 32 + fq * 8) ^ rsw)];
#pragma unroll
    for (int i = 0; i < 8; i++) {
      s16x8 a0 = *(const s16x8*)&Ap[(wm + i * 16 + fr) * 64 + ((fq * 8) ^ rsw)];
      s16x8 a1 = *(const s16x8*)&Ap[(wm + i * 16 + fr) * 64 + ((32 + fq * 8) ^ rsw)];
#pragma unroll
      for (int j = 0; j < 4; j++) {
        acc[i][j] = mfma16(a0, bfr[j][0], acc[i][j]);
        acc[i][j] = mfma16(a1, bfr[j][1], acc[i][j]);
      }
    }
    __builtin_amdgcn_s_setprio(0);
    asm volatile("s_waitcnt lgkmcnt(0)" ::: "memory");
    __builtin_amdgcn_sched_barrier(0);
    __builtin_amdgcn_s_barrier();
  }

#pragma unroll
  for (int i = 0; i < 8; i++)
#pragma unroll
    for (int j = 0; j < 4; j++)
#pragma unroll
      for (int r = 0; r < 4; r++) {
        int row = bm + wm + i * 16 + fq * 4 + r;
        int col = bn + wn + j * 16 + fr;
        if (F32OUT) ((float*)Cout)[(size_t)row * N + col] = acc[i][j][r];
        else        ((u16*)Cout)[(size_t)row * N + col] = f2bf(acc[i][j][r]);
      }
}

// ================= 128x128 pipelined GEMM (for N=2304 out-proj) =================
template <bool F32OUT>
__global__ __launch_bounds__(256) void gemm128(const u16* __restrict__ A, const u16* __restrict__ BT,
                                               void* __restrict__ Cout, int M, int N, int Kd) {
  __shared__ u16 As[2][128 * 32];
  __shared__ u16 Bs[2][128 * 32];
  int tid = threadIdx.x, lane = tid & 63, wave = tid >> 6;
  int nT = gridDim.x * gridDim.y;
  int bid = blockIdx.y * gridDim.x + blockIdx.x;
  int tile = (bid & 7) * (nT >> 3) + (bid >> 3);
  int bn = (tile % gridDim.x) * 128;
  int bm = (tile / gridDim.x) * 128;
  int wm = (wave >> 1) * 64, wn = (wave & 1) * 64;
  int fr = lane & 15, fq = lane >> 4;
  f32x4 acc[4][4];
#pragma unroll
  for (int i = 0; i < 4; i++)
#pragma unroll
    for (int j = 0; j < 4; j++) acc[i][j] = (f32x4){0.f, 0.f, 0.f, 0.f};

  int srow = tid >> 2, sslot = tid & 3;
  int scol = (sslot * 8) ^ ((srow & 3) << 3);
  const u16* Ab = A + (size_t)(bm + srow) * Kd + scol;
  const u16* Bb = BT + (size_t)(bn + srow) * Kd + scol;

  auto stage = [&](int buf, int k0) {
    async16(Ab + k0, (char*)&As[buf][0] + wave * 1024);
    async16(Ab + (size_t)64 * Kd + k0, (char*)&As[buf][0] + wave * 1024 + 4096);
    async16(Bb + k0, (char*)&Bs[buf][0] + wave * 1024);
    async16(Bb + (size_t)64 * Kd + k0, (char*)&Bs[buf][0] + wave * 1024 + 4096);
  };

  int NT = Kd >> 5;
  int rsw = (fr & 3) << 3;
  stage(0, 0);
  for (int t = 0; t < NT; ++t) {
    if (t + 1 < NT) {
      stage((t + 1) & 1, (t + 1) << 5);
      asm volatile("s_waitcnt vmcnt(4)" ::: "memory");
    } else {
      asm volatile("s_waitcnt vmcnt(0)" ::: "memory");
    }
    __builtin_amdgcn_sched_barrier(0);
    __builtin_amdgcn_s_barrier();
    __builtin_amdgcn_sched_barrier(0);
    const u16* Ap = &As[t & 1][0];
    const u16* Bp = &Bs[t & 1][0];
    __builtin_amdgcn_s_setprio(1);
    s16x8 af[4], bv[4];
#pragma unroll
    for (int i = 0; i < 4; i++) af[i] = *(const s16x8*)&Ap[(wm + i * 16 + fr) * 32 + ((fq * 8) ^ rsw)];
#pragma unroll
    for (int j = 0; j < 4; j++) bv[j] = *(const s16x8*)&Bp[(wn + j * 16 + fr) * 32 + ((fq * 8) ^ rsw)];
#pragma unroll
    for (int i = 0; i < 4; i++)
#pragma unroll
      for (int j = 0; j < 4; j++)
        acc[i][j] = mfma16(af[i], bv[j], acc[i][j]);
    __builtin_amdgcn_s_setprio(0);
    asm volatile("s_waitcnt lgkmcnt(0)" ::: "memory");
    __builtin_amdgcn_sched_barrier(0);
    __builtin_amdgcn_s_barrier();
  }
#pragma unroll
  for (int i = 0; i < 4; i++)
#pragma unroll
    for (int j = 0; j < 4; j++)
#pragma unroll
      for (int r = 0; r < 4; r++) {
        int row = bm + wm + i * 16 + fq * 4 + r;
        int col = bn + wn + j * 16 + fr;
        if (F32OUT) ((float*)Cout)[(size_t)row * N + col] = acc[i][j][r];
        else        ((u16*)Cout)[(size_t)row * N + col] = f2bf(acc[i][j][r]);
      }
}

// ---------------- RoPE sin/cos table: [pos 0..S-1][d 0..127] f32 ----------------
__global__ void rope_table(float* __restrict__ ct, float* __restrict__ st) {
  int t = blockIdx.x * blockDim.x + threadIdx.x;   // t = p*128 + d
  int d = t & 127;
  int p = t >> 7;
  float invf = exp2f(-(float)d * 0.1038102530f); // log2(10000)/128
  float f = (float)p * invf;
  float s, c;
  sincosf(f, &s, &c);
  ct[t] = c;
  st[t] = s;
}

// ---------------- RoPE on K columns of fused QKV (8 pairs per thread) ----------------
__global__ void rope_k(u16* __restrict__ QKV, const int* __restrict__ pos_ids,
                       const float* __restrict__ ct, const float* __restrict__ st) {
  int t = blockIdx.x * blockDim.x + threadIdx.x;   // 4096 rows * 4 heads * 16 dgroups
  int dg = t & 15, h = (t >> 4) & 3, row = t >> 6;
  u16* p1 = QKV + (size_t)row * 4096 + 2048 + h * 256 + dg * 8;
  u16* p2 = p1 + 128;
  int pos = pos_ids[row];
  const float* ctp = ct + pos * 128 + dg * 8;
  const float* stp = st + pos * 128 + dg * 8;
  s16x8 v1 = *(const s16x8*)p1, v2 = *(const s16x8*)p2;
#pragma unroll
  for (int j = 0; j < 8; j++) {
    float c = ctp[j], s = stp[j];
    float a = bf2f((u16)v1[j]);
    float b = bf2f((u16)v2[j]);
    v1[j] = (short)f2bf(a * c - b * s);
    v2[j] = (short)f2bf(b * c + a * s);
  }
  *(s16x8*)p1 = v1;
  *(s16x8*)p2 = v2;
}

// ---------------- flash attention: counted-vmcnt pipeline, softcap, fixed-max softmax ----
// Balanced flat grid (512): id<256 -> qt=31-(id>>4) heavy, else qt=(id-256)>>4; pair shares (b,h).
// Per-tile schedule (gemm256-style): stage(t+1) -> vmcnt(8) -> s_barrier -> QK^T -> softmax
// -> P write -> lgkm0 -> PV -> lgkm0 -> s_barrier.  vmcnt NEVER drained in the loop.
// amask pre-packed to an LDS byte-mask so no vmem ops pollute the counted vmcnt.
__global__ __launch_bounds__(256) void attn_kernel(const u16* __restrict__ QKV, const u16* __restrict__ VT,
                                                   const int* __restrict__ amask, const int* __restrict__ pos_ids,
                                                   const float* __restrict__ ct, const float* __restrict__ st,
                                                   u16* __restrict__ O) {
  __shared__ u16 Kl[2][32 * 256];        // [buf][key][hd]  swizzled ^((key&7)<<3)
  __shared__ u16 Vl[2][256 * 32];        // [buf][hd][key]  swizzled ^((hd&3)<<3)
  __shared__ u16 Pl[4][16 * 40];         // per-wave P, rows padded to 80B
  __shared__ unsigned char Ml[2048];     // amask bytes for this b
  int id = blockIdx.x;
  int qt, bh;
  if (id < 256) { qt = 31 - (id >> 4); bh = id & 15; }
  else          { qt = (id - 256) >> 4; bh = (id - 256) & 15; }
  int b = bh >> 3, h = bh & 7, g = h >> 1;
  int tid = threadIdx.x, lane = tid & 63, wave = tid >> 6;
  int fr = lane & 15, fq = lane >> 4;
  int q0 = qt * 64;

  // ---- pack attention mask to LDS bytes (8 ints -> 8 bytes per thread) ----
  const int* amp = amask + b * S_;
  {
    int base = tid * 8;
    int4 a = *(const int4*)(amp + base);
    int4 c = *(const int4*)(amp + base + 4);
    uint64_t w = 0;
    w |= (uint64_t)(a.x > 0 ? 1 : 0);
    w |= (uint64_t)(a.y > 0 ? 1 : 0) << 8;
    w |= (uint64_t)(a.z > 0 ? 1 : 0) << 16;
    w |= (uint64_t)(a.w > 0 ? 1 : 0) << 24;
    w |= (uint64_t)(c.x > 0 ? 1 : 0) << 32;
    w |= (uint64_t)(c.y > 0 ? 1 : 0) << 40;
    w |= (uint64_t)(c.z > 0 ? 1 : 0) << 48;
    w |= (uint64_t)(c.w > 0 ? 1 : 0) << 56;
    *(uint64_t*)&Ml[base] = w;
  }

  // ---- load Q row fragment + apply RoPE in-register (pairs (d,d+128) are lane-local) ----
  int qrow_g = b * S_ + q0 + wave * 16 + fr;
  s16x8 qr[8];
  const u16* qb = QKV + (size_t)qrow_g * 4096 + h * 256 + fq * 8;
#pragma unroll
  for (int kk = 0; kk < 8; kk++) qr[kk] = *(const s16x8*)(qb + kk * 32);
  int pos = pos_ids[qrow_g];
  const float* ctp = ct + pos * 128 + fq * 8;
  const float* stp = st + pos * 128 + fq * 8;
  s16x8 qf[8];
#pragma unroll
  for (int kk = 0; kk < 4; kk++) {
#pragma unroll
    for (int j = 0; j < 8; j++) {
      float c = ctp[kk * 32 + j], s = stp[kk * 32 + j];
      float a = bf2f((u16)qr[kk][j]);
      float bb = bf2f((u16)qr[kk + 4][j]);
      qf[kk][j]     = (short)f2bf((a * c - bb * s) * 0.0625f);   // 1/sqrt(256)
      qf[kk + 4][j] = (short)f2bf((bb * c + a * s) * 0.0625f);
    }
  }

  f32x4 zero4 = {0.f, 0.f, 0.f, 0.f};
  f32x4 oacc[16];
#pragma unroll
  for (int i = 0; i < 16; i++) oacc[i] = zero4;
  f32x4 lacc = zero4;                                     // softmax denominator via ones-MFMA
  s16x8 onesv;
#pragma unroll
  for (int i = 0; i < 8; i++) onesv[i] = (short)0x3F80;   // bf16 1.0

  const u16* Kbase = QKV + (size_t)b * S_ * 4096 + 2048 + g * 256;
  const u16* Vbase = VT + (size_t)(b * 4 + g) * 256 * S_;

  auto stage = [&](int buf, int k0) {
#pragma unroll
    for (int it = 0; it < 4; ++it) {
      int rl = it * 2 + (lane >> 5);
      int kce = ((lane & 31) * 8) ^ ((rl & 7) << 3);
      async16(Kbase + (size_t)(k0 + wave * 8 + rl) * 4096 + kce,
              (char*)&Kl[buf][0] + wave * 4096 + it * 1024);
      int dl = wave * 64 + it * 16 + (lane >> 2);
      int vce = ((lane & 3) * 8) ^ (((lane >> 2) & 3) << 3);
      async16(Vbase + (size_t)dl * 2048 + k0 + vce,
              (char*)&Vl[buf][0] + wave * 4096 + it * 1024);
    }
  };

  int nt = 2 * qt + 2;                                        // 32-key tiles
  __syncthreads();                                            // Ml ready; drains everything
  stage(0, 0);                                                // 8 loads in flight
  int buf = 0;
  int ksw = (fr & 7) << 3;
  int vsw = (fr & 3) << 3;
  for (int t = 0; t < nt; ++t) {
    int k0 = t * 32;
    if (t + 1 < nt) {
      stage(buf ^ 1, k0 + 32);                                // +8 -> 16 in flight
      asm volatile("s_waitcnt vmcnt(8)" ::: "memory");        // tile t landed; t+1 in flight
    } else {
      asm volatile("s_waitcnt vmcnt(0)" ::: "memory");
    }
    __builtin_amdgcn_sched_barrier(0);
    __builtin_amdgcn_s_barrier();
    __builtin_amdgcn_sched_barrier(0);

    int am0 = Ml[k0 + fr];
    int am1 = Ml[k0 + 16 + fr];

    __builtin_amdgcn_s_setprio(1);
    f32x4 sA[2][2] = {{zero4, zero4}, {zero4, zero4}};        // 2-way dep-chain split
#pragma unroll
    for (int kk = 0; kk < 8; kk++) {
      s16x8 b0 = *(const s16x8*)&Kl[buf][fr * 256 + ((kk * 32 + fq * 8) ^ ksw)];
      s16x8 b1 = *(const s16x8*)&Kl[buf][(16 + fr) * 256 + ((kk * 32 + fq * 8) ^ ksw)];
      sA[0][kk & 1] = mfma16(qf[kk], b0, sA[0][kk & 1]);
      sA[1][kk & 1] = mfma16(qf[kk], b1, sA[1][kk & 1]);
    }
    __builtin_amdgcn_s_setprio(0);
    f32x4 s0 = sA[0][0] + sA[0][1];
    f32x4 s1 = sA[1][0] + sA[1][1];

    bool needmask = (t >= nt - 2);
#pragma unroll
    for (int r = 0; r < 4; r++) {
      int qrow = fq * 4 + r;
      int qg = q0 + wave * 16 + qrow;
      // p = exp(50*tanh(s/50) - 50) = exp(-100/(exp(0.04*s)+1))   [fixed max = 50]
      float e20 = __expf(s0[r] * 0.04f);
      float e21 = __expf(s1[r] * 0.04f);
      float p0 = __expf(__fdividef(-100.f, e20 + 1.f));
      float p1 = __expf(__fdividef(-100.f, e21 + 1.f));
      bool ok0 = (am0 > 0) && (!needmask || (k0 + fr) <= qg);
      bool ok1 = (am1 > 0) && (!needmask || (k0 + 16 + fr) <= qg);
      p0 = ok0 ? p0 : 0.f;
      p1 = ok1 ? p1 : 0.f;
      Pl[wave][qrow * 40 + fr] = f2bf(p0);
      Pl[wave][qrow * 40 + 16 + fr] = f2bf(p1);
    }
    asm volatile("s_waitcnt lgkmcnt(0)" ::: "memory");
    __builtin_amdgcn_sched_barrier(0);

    s16x8 pf = *(const s16x8*)&Pl[wave][fr * 40 + fq * 8];
    __builtin_amdgcn_s_setprio(1);
    lacc = mfma16(pf, onesv, lacc);
#pragma unroll
    for (int df = 0; df < 16; df++) {
      s16x8 vv = *(const s16x8*)&Vl[buf][(df * 16 + fr) * 32 + ((fq * 8) ^ vsw)];
      oacc[df] = mfma16(pf, vv, oacc[df]);
    }
    __builtin_amdgcn_s_setprio(0);
    asm volatile("s_waitcnt lgkmcnt(0)" ::: "memory");        // ds reads of buf done (NOT vmcnt)
    __builtin_amdgcn_sched_barrier(0);
    __builtin_amdgcn_s_barrier();
    buf ^= 1;
  }

  float rinv[4];
#pragma unroll
  for (int r = 0; r < 4; r++) rinv[r] = 1.0f / lacc[r];
#pragma unroll
  for (int df = 0; df < 16; df++) {
#pragma unroll
    for (int r = 0; r < 4; r++) {
      float ov = oacc[df][r] * rinv[r];
      O[(size_t)(b * S_ + q0 + wave * 16 + fq * 4 + r) * 2048 + h * 256 + df * 16 + fr] = f2bf(ov);
    }
  }
}

extern "C" void kernel_launch(void* const* d_in, const int* in_sizes, int n_in,
                              void* d_out, int out_size, void* d_ws, size_t ws_size,
                              hipStream_t stream) {
  const float* X   = (const float*)d_in[0];   // [B,S,H] fp32
  const int* amask = (const int*)d_in[1];
  const int* pos   = (const int*)d_in[2];
  const float* Wq  = (const float*)d_in[3];
  const float* Wk  = (const float*)d_in[4];
  const float* Wv  = (const float*)d_in[5];
  const float* Wo  = (const float*)d_in[6];
  float* out = (float*)d_out;                 // [B,S,H] fp32

  char* ws = (char*)d_ws;
  size_t off = 0;
  auto allocB = [&](size_t bytes) {
    char* p = ws + off;
    off += ((bytes + 255) & ~(size_t)255);
    return p;
  };
  u16* Xb   = (u16*)allocB((size_t)4096 * 2304 * 2);
  u16* WqT  = (u16*)allocB((size_t)2048 * 2304 * 2);   // WqT/WkT/WvT contiguous => fused B^T
  u16* WkT  = (u16*)allocB((size_t)1024 * 2304 * 2);
  u16* WvT  = (u16*)allocB((size_t)1024 * 2304 * 2);
  u16* WoT  = (u16*)allocB((size_t)2304 * 2048 * 2);
  u16* QKV  = (u16*)allocB((size_t)4096 * 4096 * 2);
  u16* VTb  = (u16*)allocB((size_t)4096 * 1024 * 2);
  u16* AO   = (u16*)allocB((size_t)4096 * 2048 * 2);
  float* CT = (float*)allocB((size_t)2048 * 128 * 4);
  float* ST = (float*)allocB((size_t)2048 * 128 * 4);
  if (off > ws_size) return;

  // RoPE table (independent; early)
  rope_table<<<(2048 * 128) / 256, 256, 0, stream>>>(CT, ST);

  // hidden_states fp32 -> bf16
  {
    size_t n = (size_t)4096 * 2304;
    f32_to_bf16<<<(unsigned)((n / 4 + 255) / 256), 256, 0, stream>>>(X, Xb, n);
  }

  dim3 tb(32, 8);
  transpose_f32_bf16<<<dim3(2048 / 32, 2304 / 32), tb, 0, stream>>>(Wq, WqT, 2304, 2048);
  transpose_f32_bf16<<<dim3(1024 / 32, 2304 / 32), tb, 0, stream>>>(Wk, WkT, 2304, 1024);
  transpose_f32_bf16<<<dim3(1024 / 32, 2304 / 32), tb, 0, stream>>>(Wv, WvT, 2304, 1024);
  transpose_f32_bf16<<<dim3(2304 / 32, 2048 / 32), tb, 0, stream>>>(Wo, WoT, 2048, 2304);

  // fused QKV projection (256² pipelined)
  gemm256<false><<<dim3(4096 / 256, 4096 / 256), 512, 0, stream>>>(Xb, WqT, QKV, 4096, 4096, 2304);

  // RoPE on K only (Q roped in-register inside attn)
  rope_k<<<(4096 * 4 * 16) / 256, 256, 0, stream>>>(QKV, pos, CT, ST);

  // V (QKV cols 3072..4095) -> VT[b][kv][d][s]
  transpose_bf16_s<<<dim3(1024 / 32, 2048 / 32, 2), tb, 0, stream>>>(
      QKV + 3072, VTb, 2048, 1024, 4096, (size_t)2048 * 4096, (size_t)1024 * 2048);

  // attention (balanced flat grid, counted-vmcnt pipeline)
  attn_kernel<<<dim3(512), 256, 0, stream>>>(QKV, VTb, amask, pos, CT, ST, AO);

  // output projection -> fp32 d_out (128² pipelined)
  gemm128<true><<<dim3(2304 / 128, 4096 / 128), 256, 0, stream>>>(AO, WoT, out, 4096, 2304, 2048);
}